// Round 2
// baseline (564.295 us; speedup 1.0000x reference)
//
#include <hip/hip_runtime.h>
#include <hip/hip_bf16.h>
#include <stdint.h>

// Problem constants
#define B_    2
#define T_    2048
#define E_    1024
#define H_    16
#define D_    64
#define NTOK  (B_*T_)   // 4096

typedef unsigned short u16;
typedef short s16x8 __attribute__((ext_vector_type(8)));
typedef float f32x4 __attribute__((ext_vector_type(4)));

// ---------- helpers ----------
__device__ __forceinline__ u16 f2bf(float f) {
  uint32_t u = __float_as_uint(f);
  u += 0x7FFFu + ((u >> 16) & 1u);          // RNE
  return (u16)(u >> 16);
}
__device__ __forceinline__ float bf2f(u16 h) {
  return __uint_as_float(((uint32_t)h) << 16);
}
__device__ __forceinline__ void split2(float v, u16 &h, u16 &l) {
  h = f2bf(v);
  l = f2bf(v - bf2f(h));
}

// async global->LDS, 16B per lane (linear dest = wave base + lane*16)
__device__ __forceinline__ void gload_lds16(const void* g, void* l) {
  void* gnc = const_cast<void*>(g);
  __builtin_amdgcn_global_load_lds(
      (__attribute__((address_space(1))) uint32_t*)gnc,
      (__attribute__((address_space(3))) uint32_t*)l, 16, 0, 0);
}

// MFMA via inline asm (D,A,B,C); "+v" ties C=D so compiler tracks the dep.
#define MFMA_BF16(accv, av, bv) \
  asm("v_mfma_f32_16x16x32_bf16 %0, %1, %2, %0" : "+v"(accv) : "v"(av), "v"(bv))

// ---------- split f32 -> bf16 hi/lo ----------
__global__ __launch_bounds__(256) void k_split(const float* __restrict__ in,
                                               u16* __restrict__ hi,
                                               u16* __restrict__ lo, int n4) {
  int i = blockIdx.x * 256 + threadIdx.x;
  if (i >= n4) return;
  float4 v = ((const float4*)in)[i];
  u16 h0,h1,h2,h3,l0,l1,l2,l3;
  split2(v.x,h0,l0); split2(v.y,h1,l1); split2(v.z,h2,l2); split2(v.w,h3,l3);
  ushort4 hv; hv.x=h0; hv.y=h1; hv.z=h2; hv.w=h3;
  ushort4 lv; lv.x=l0; lv.y=l1; lv.z=l2; lv.w=l3;
  ((ushort4*)hi)[i] = hv;
  ((ushort4*)lo)[i] = lv;
}

// ---------- split-bf16 NT GEMM: C[M,N] = A[M,K] * Bt[N,K]^T ----------
// 128x64 tile, BK=32, 256 thr (2x2 waves of 64x32), 16x16x32 MFMA,
// 3 MFMA/frag (hi*hi + hi*lo + lo*hi). Grid (N/64, M/128, batches).
__global__ __launch_bounds__(256) void gemm_nt_split(
    const u16* __restrict__ Ahi, const u16* __restrict__ Alo,
    const u16* __restrict__ Bhi, const u16* __restrict__ Blo,
    float* __restrict__ C, int M, int N, int K,
    long long sA, long long sB, long long sC, int causal) {
  const int bz = blockIdx.z;
  Ahi += (size_t)bz * sA; Alo += (size_t)bz * sA;
  Bhi += (size_t)bz * sB; Blo += (size_t)bz * sB;
  C   += (size_t)bz * sC;

  const int m0 = blockIdx.y * 128;
  const int n0 = blockIdx.x * 64;
  const int tid  = threadIdx.x;
  const int lane = tid & 63;
  const int w    = tid >> 6;
  const int wm = w >> 1, wn = w & 1;
  const int kmax = causal ? ((m0 + 128 < K) ? (m0 + 128) : K) : K;

  __shared__ u16 sAhi[128*32], sAlo[128*32], sBhi[64*32], sBlo[64*32]; // 24 KiB

  const int r0 = tid >> 2;            // 0..63
  const int c0 = (tid & 3) * 8;       // k element offset (16B chunks)
  const size_t arow  = (size_t)(m0 + r0) * K;
  const size_t arow2 = (size_t)(m0 + 64 + r0) * K;
  const size_t brow  = (size_t)(n0 + r0) * K;
  const int ldso = r0 * 32 + c0;      // == tid*16 bytes (linear per wave)

  f32x4 acc[4][2] = {};

  for (int k0 = 0; k0 < kmax; k0 += 32) {
    const int kc = k0 + c0;
    gload_lds16(Ahi + arow  + kc, &sAhi[ldso]);
    gload_lds16(Ahi + arow2 + kc, &sAhi[64*32 + ldso]);
    gload_lds16(Alo + arow  + kc, &sAlo[ldso]);
    gload_lds16(Alo + arow2 + kc, &sAlo[64*32 + ldso]);
    gload_lds16(Bhi + brow  + kc, &sBhi[ldso]);
    gload_lds16(Blo + brow  + kc, &sBlo[ldso]);
    __syncthreads();   // compiler drains vmcnt before s_barrier

    const int la = lane & 15;
    const int ka = (lane >> 4) * 8;
    s16x8 ah[4], al[4], bh[2], bl[2];
    #pragma unroll
    for (int i = 0; i < 4; ++i) {
      const int ar = (wm*64 + i*16 + la) * 32 + ka;
      ah[i] = *(const s16x8*)&sAhi[ar];
      al[i] = *(const s16x8*)&sAlo[ar];
    }
    #pragma unroll
    for (int j = 0; j < 2; ++j) {
      const int br = (wn*32 + j*16 + la) * 32 + ka;
      bh[j] = *(const s16x8*)&sBhi[br];
      bl[j] = *(const s16x8*)&sBlo[br];
    }
    #pragma unroll
    for (int i = 0; i < 4; ++i) {
      #pragma unroll
      for (int j = 0; j < 2; ++j) {
        MFMA_BF16(acc[i][j], al[i], bh[j]);
        MFMA_BF16(acc[i][j], ah[i], bl[j]);
        MFMA_BF16(acc[i][j], ah[i], bh[j]);
      }
    }
    __syncthreads();
  }

  asm volatile("s_nop 7\n\ts_nop 7\n\ts_nop 7" ::);  // MFMA->VALU read hazard guard

  const int cr = (lane >> 4) * 4;
  const int cc = lane & 15;
  #pragma unroll
  for (int i = 0; i < 4; ++i) {
    #pragma unroll
    for (int j = 0; j < 2; ++j) {
      const size_t row = (size_t)(m0 + wm*64 + i*16 + cr);
      const int col = n0 + wn*32 + j*16 + cc;
      float* cp = C + row * N + col;
      cp[0]             = acc[i][j][0];
      cp[(size_t)N]     = acc[i][j][1];
      cp[(size_t)2*N]   = acc[i][j][2];
      cp[(size_t)3*N]   = acc[i][j][3];
    }
  }
}

// ---------- sc2 = ||echo_row||^2 / 32  (one wave per token) ----------
__global__ __launch_bounds__(256) void k_sc2(const float* __restrict__ echo,
                                             float* __restrict__ sc2) {
  int tok  = blockIdx.x * 4 + (threadIdx.x >> 6);
  int lane = threadIdx.x & 63;
  const float4* p = (const float4*)(echo + (size_t)tok * E_);
  float s = 0.f;
  #pragma unroll
  for (int j = 0; j < 4; ++j) {
    float4 v = p[lane + j*64];
    s += v.x*v.x + v.y*v.y + v.z*v.z + v.w*v.w;
  }
  #pragma unroll
  for (int off = 32; off; off >>= 1) s += __shfl_xor(s, off);
  if (lane == 0) sc2[tok] = s * (1.0f/32.0f);
}

// ---------- echo f32 [b][t][e] -> echoT hi/lo bf16 [b][e][t] ----------
__global__ __launch_bounds__(256) void k_tsplit(const float* __restrict__ echo,
                                                u16* __restrict__ Thi,
                                                u16* __restrict__ Tlo) {
  __shared__ float tile[32][33];
  int b = blockIdx.z;
  int t0 = blockIdx.x * 32, e0 = blockIdx.y * 32;
  int lx = threadIdx.x & 31, ly = threadIdx.x >> 5;
  #pragma unroll
  for (int i = 0; i < 32; i += 8)
    tile[ly + i][lx] = echo[((size_t)b*T_ + t0 + ly + i) * E_ + e0 + lx];
  __syncthreads();
  #pragma unroll
  for (int i = 0; i < 32; i += 8) {
    float v = tile[lx][ly + i];
    size_t o = ((size_t)b*E_ + e0 + ly + i) * T_ + t0 + lx;
    u16 h, l; split2(v, h, l);
    Thi[o] = h; Tlo[o] = l;
  }
}

// ---------- ra[b,h,t] = sum_e x[b,t,e]*wr[h,e,t] ----------
__global__ __launch_bounds__(256) void k_ra(const float* __restrict__ x,
                                            const float* __restrict__ wr,
                                            float* __restrict__ ra) {
  int t  = blockIdx.x * 256 + threadIdx.x;
  int h  = blockIdx.y;
  int ec = blockIdx.z;                       // e-chunk of 256
  const float* wrp = wr + ((size_t)h * E_ + ec * 256) * T_ + t;
  const float* x0  = x + (size_t)t * E_ + ec * 256;
  const float* x1  = x0 + (size_t)T_ * E_;
  float a0 = 0.f, a1 = 0.f;
  #pragma unroll 8
  for (int e = 0; e < 256; ++e) {
    float w = wrp[(size_t)e * T_];
    a0 = fmaf(x0[e], w, a0);
    a1 = fmaf(x1[e], w, a1);
  }
  atomicAdd(&ra[(size_t)h * T_ + t], a0);
  atomicAdd(&ra[(size_t)(H_ + h) * T_ + t], a1);
}

// ---------- RRP pass 1: global max + 64-t chunk sums ----------
__global__ __launch_bounds__(256) void k_rrp1(const float* __restrict__ ra,
    const float* __restrict__ rv, float* __restrict__ gmaxb,
    float* __restrict__ csnum, float* __restrict__ csden) {
  int bh = blockIdx.x;                  // b*16+h
  int b = bh >> 4, h = bh & 15;
  int tid = threadIdx.x;
  const float* rar = ra + (size_t)bh * T_;
  __shared__ float red[256];
  float mx = -1e30f;
  for (int t = tid; t < T_; t += 256) mx = fmaxf(mx, rar[t]);
  red[tid] = mx; __syncthreads();
  for (int s = 128; s > 0; s >>= 1) {
    if (tid < s) red[tid] = fmaxf(red[tid], red[tid + s]);
    __syncthreads();
  }
  float gm = red[0] * 0.125f;
  if (tid == 0) gmaxb[bh] = gm;
  int w = tid >> 6, lane = tid & 63;
  for (int c = w; c < 32; c += 4) {
    float num = 0.f, den = 0.f;
    int t0 = c * 64;
    const float* rvp = rv + ((size_t)b * T_ + t0) * E_ + h * 64 + lane;
    #pragma unroll 4
    for (int i = 0; i < 64; ++i) {
      float wt = __expf(fmaf(rar[t0 + i], 0.125f, -gm));
      num = fmaf(wt, rvp[(size_t)i * E_], num);
      den += wt;
    }
    csnum[((size_t)bh * 32 + c) * 64 + lane] = num;
    if (lane == 0) csden[bh * 32 + c] = den;
  }
}

// ---------- RRP pass 2: carry-in + in-chunk scan, write rrp ----------
__global__ __launch_bounds__(64) void k_rrp2(const float* __restrict__ ra,
    const float* __restrict__ rv, const float* __restrict__ gmaxb,
    const float* __restrict__ csnum, const float* __restrict__ csden,
    float* __restrict__ rrp) {
  int bh = blockIdx.x, c = blockIdx.y;
  int b = bh >> 4, h = bh & 15;
  int lane = threadIdx.x;
  float gm = gmaxb[bh];
  const float* rar = ra + (size_t)bh * T_;
  float num = 0.f, den = 0.f;
  for (int cc = 0; cc < c; ++cc) {
    num += csnum[((size_t)bh * 32 + cc) * 64 + lane];
    den += csden[bh * 32 + cc];
  }
  int t0 = c * 64;
  const float* rvp = rv  + ((size_t)b * T_ + t0) * E_ + h * 64 + lane;
  float*       op  = rrp + ((size_t)b * T_ + t0) * E_ + h * 64 + lane;
  for (int i = 0; i < 64; ++i) {
    float wt = __expf(fmaf(rar[t0 + i], 0.125f, -gm));
    num = fmaf(wt, rvp[(size_t)i * E_], num);
    den += wt;
    op[(size_t)i * E_] = num / den;
  }
}

// ---------- Janus: inclusive prefix-max scan of sc2 (per batch) ----------
__global__ __launch_bounds__(256) void k_pmax(const float* __restrict__ sc2,
                                              float* __restrict__ pmax) {
  int b = blockIdx.x;
  __shared__ float u[T_];
  int tid = threadIdx.x;
  for (int i = tid; i < T_; i += 256) u[i] = sc2[b*T_ + i];
  __syncthreads();
  for (int off = 1; off < T_; off <<= 1) {
    float v[8];
    #pragma unroll
    for (int k = 0; k < 8; ++k) {
      int i = tid + k*256;
      v[k] = (i >= off) ? fmaxf(u[i], u[i-off]) : u[i];
    }
    __syncthreads();
    #pragma unroll
    for (int k = 0; k < 8; ++k) u[tid + k*256] = v[k];
    __syncthreads();
  }
  for (int i = tid; i < T_; i += 256) pmax[b*T_ + i] = u[i];
}

// ---------- Janus: row max m_s = a_s*pmax_s and denominator (wave/row) ----------
__global__ __launch_bounds__(256) void k_jden(const float* __restrict__ sc2,
    const float* __restrict__ pmax, float* __restrict__ jm,
    float* __restrict__ jden) {
  int b = blockIdx.y;
  int s = blockIdx.x * 4 + (threadIdx.x >> 6);
  int lane = threadIdx.x & 63;
  const float* u = sc2 + b*T_;
  float a = u[s];
  float m = a * pmax[b*T_ + s];
  float d = 0.f;
  for (int t = lane; t <= s; t += 64) d += __expf(fmaf(a, u[t], -m));
  #pragma unroll
  for (int off = 32; off; off >>= 1) d += __shfl_xor(d, off);
  if (lane == 0) { jm[b*T_+s] = m; jden[b*T_+s] = d; }
}

// ---------- materialize P (hi/lo bf16), normalized, causal-zeroed ----------
__global__ __launch_bounds__(256) void k_pgen(const float* __restrict__ sc2,
    const float* __restrict__ jm, const float* __restrict__ jden,
    u16* __restrict__ Phi, u16* __restrict__ Plo) {
  int b = blockIdx.z;
  size_t base = ((size_t)blockIdx.x * 256 + threadIdx.x) * 8;
  int s  = (int)(base >> 11);
  int t0 = (int)(base & 2047);
  const float* u = sc2 + b*T_;
  float a = u[s];
  float m = jm[b*T_+s];
  float invd = 1.0f / jden[b*T_+s];
  u16 hh[8], ll[8];
  #pragma unroll
  for (int k = 0; k < 8; ++k) {
    int tt = t0 + k;
    float p = (tt <= s) ? __expf(fmaf(a, u[tt], -m)) * invd : 0.0f;
    split2(p, hh[k], ll[k]);
  }
  size_t o = ((size_t)b*T_ + s) * T_ + t0;
  ushort4 h0; h0.x=hh[0]; h0.y=hh[1]; h0.z=hh[2]; h0.w=hh[3];
  ushort4 h1; h1.x=hh[4]; h1.y=hh[5]; h1.z=hh[6]; h1.w=hh[7];
  ushort4 l0; l0.x=ll[0]; l0.y=ll[1]; l0.z=ll[2]; l0.w=ll[3];
  ushort4 l1; l1.x=ll[4]; l1.y=ll[5]; l1.z=ll[6]; l1.w=ll[7];
  *(ushort4*)(Phi + o)     = h0; *(ushort4*)(Phi + o + 4) = h1;
  *(ushort4*)(Plo + o)     = l0; *(ushort4*)(Plo + o + 4) = l1;
}

// ---------- gated fuse -> bf16 hi/lo ----------
__global__ __launch_bounds__(256) void k_fuse(const float* __restrict__ rrp,
    const float* __restrict__ jan, const float* __restrict__ gate,
    u16* __restrict__ Fhi, u16* __restrict__ Flo) {
  int i = blockIdx.x * 256 + threadIdx.x;      // float4 index
  int h = (i & 255) >> 4;                      // ((i*4) % 1024) / 64
  float g0 = gate[h*2], g1 = gate[h*2+1];
  float mg = fmaxf(g0, g1);
  float e0 = __expf(g0 - mg), e1 = __expf(g1 - mg);
  float inv = 1.0f / (e0 + e1);
  float w0 = e0 * inv, w1 = e1 * inv;
  float4 r = ((const float4*)rrp)[i];
  float4 j = ((const float4*)jan)[i];
  u16 hh[4], ll[4];
  split2(w0*r.x + w1*j.x, hh[0], ll[0]);
  split2(w0*r.y + w1*j.y, hh[1], ll[1]);
  split2(w0*r.z + w1*j.z, hh[2], ll[2]);
  split2(w0*r.w + w1*j.w, hh[3], ll[3]);
  ushort4 hv; hv.x=hh[0]; hv.y=hh[1]; hv.z=hh[2]; hv.w=hh[3];
  ushort4 lv; lv.x=ll[0]; lv.y=ll[1]; lv.z=ll[2]; lv.w=ll[3];
  ((ushort4*)Fhi)[i] = hv;
  ((ushort4*)Flo)[i] = lv;
}

// ---------- launcher ----------
extern "C" void kernel_launch(void* const* d_in, const int* in_sizes, int n_in,
                              void* d_out, int out_size, void* d_ws, size_t ws_size,
                              hipStream_t stream) {
  const float* x    = (const float*)d_in[0];
  const float* wr   = (const float*)d_in[1];
  const float* wvr  = (const float*)d_in[2];
  const float* wj   = (const float*)d_in[3];
  const float* gate = (const float*)d_in[4];
  const float* wo   = (const float*)d_in[5];
  float* out = (float*)d_out;

  char* p = (char*)d_ws;
  auto alloc = [&](size_t bytes) {
    char* r = p;
    p += (bytes + 255) & ~(size_t)255;
    return r;
  };
  // ~131 MB total workspace
  u16* x_hi   = (u16*)alloc((size_t)NTOK*E_*2);
  u16* x_lo   = (u16*)alloc((size_t)NTOK*E_*2);
  u16* wvr_hi = (u16*)alloc((size_t)E_*E_*2);
  u16* wvr_lo = (u16*)alloc((size_t)E_*E_*2);
  u16* wj_hi  = (u16*)alloc((size_t)E_*E_*2);
  u16* wj_lo  = (u16*)alloc((size_t)E_*E_*2);
  u16* wo_hi  = (u16*)alloc((size_t)E_*E_*2);
  u16* wo_lo  = (u16*)alloc((size_t)E_*E_*2);
  float* rv   = (float*)alloc((size_t)NTOK*E_*4);   // later reused as jan
  float* echo = (float*)alloc((size_t)NTOK*E_*4);   // later reused as p_hi
  u16* p_lo   = (u16*)alloc((size_t)B_*T_*T_*2);
  u16* eT_hi  = (u16*)alloc((size_t)B_*E_*T_*2);
  u16* eT_lo  = (u16*)alloc((size_t)B_*E_*T_*2);
  float* sc2  = (float*)alloc((size_t)NTOK*4);
  float* ra   = (float*)alloc((size_t)B_*H_*T_*4);
  float* gmaxb= (float*)alloc(32*4);
  float* csnum= (float*)alloc((size_t)32*32*64*4);
  float* csden= (float*)alloc((size_t)32*32*4);
  float* pmaxv= (float*)alloc((size_t)NTOK*4);
  float* jm   = (float*)alloc((size_t)NTOK*4);
  float* jden = (float*)alloc((size_t)NTOK*4);
  float* rrp  = (float*)alloc((size_t)NTOK*E_*4);
  u16* f_hi   = (u16*)alloc((size_t)NTOK*E_*2);
  u16* f_lo   = (u16*)alloc((size_t)NTOK*E_*2);
  u16* p_hi = (u16*)echo;   // alias: echo f32 dead before pgen
  float* jan = rv;          // alias: rv dead before jan GEMM

  int n4;
  // split conversions
  n4 = NTOK*E_/4; k_split<<<dim3((n4+255)/256),256,0,stream>>>(x,   x_hi,   x_lo,   n4);
  n4 = E_*E_/4;   k_split<<<dim3((n4+255)/256),256,0,stream>>>(wvr, wvr_hi, wvr_lo, n4);
                  k_split<<<dim3((n4+255)/256),256,0,stream>>>(wj,  wj_hi,  wj_lo,  n4);
                  k_split<<<dim3((n4+255)/256),256,0,stream>>>(wo,  wo_hi,  wo_lo,  n4);

  // rv = x @ wvr^T ; echo = x @ wj^T   (grid: N/64 x M/128)
  gemm_nt_split<<<dim3(16,32,1),256,0,stream>>>(x_hi,x_lo,wvr_hi,wvr_lo,rv,  NTOK,E_,E_, 0,0,0, 0);
  gemm_nt_split<<<dim3(16,32,1),256,0,stream>>>(x_hi,x_lo,wj_hi, wj_lo, echo,NTOK,E_,E_, 0,0,0, 0);

  // sc2 (analytic ||echo||^2/sqrt(E)), echoT hi/lo
  k_sc2<<<dim3(NTOK/4),256,0,stream>>>(echo, sc2);
  k_tsplit<<<dim3(T_/32, E_/32, B_),256,0,stream>>>(echo, eT_hi, eT_lo);

  // ra (per-head key scores)
  hipMemsetAsync(ra, 0, (size_t)B_*H_*T_*4, stream);
  k_ra<<<dim3(T_/256, H_, 4),256,0,stream>>>(x, wr, ra);

  // RRP prefix-softmax scan
  k_rrp1<<<dim3(32),256,0,stream>>>(ra, rv, gmaxb, csnum, csden);
  k_rrp2<<<dim3(32,32),64,0,stream>>>(ra, rv, gmaxb, csnum, csden, rrp);

  // Janus stats + P + PV GEMM (causal)
  k_pmax<<<dim3(B_),256,0,stream>>>(sc2, pmaxv);
  k_jden<<<dim3(T_/4, B_),256,0,stream>>>(sc2, pmaxv, jm, jden);
  k_pgen<<<dim3(T_*T_/2048, 1, B_),256,0,stream>>>(sc2, jm, jden, p_hi, p_lo);
  gemm_nt_split<<<dim3(16,16,2),256,0,stream>>>(p_hi,p_lo,eT_hi,eT_lo,jan, T_,E_,T_,
      (long long)T_*T_, (long long)E_*T_, (long long)T_*E_, 1);

  // fuse + final projection
  n4 = NTOK*E_/4;
  k_fuse<<<dim3(n4/256),256,0,stream>>>(rrp, jan, gate, f_hi, f_lo);
  gemm_nt_split<<<dim3(16,32,1),256,0,stream>>>(f_hi,f_lo,wo_hi,wo_lo,out, NTOK,E_,E_, 0,0,0, 0);
}

// Round 5
// 535.949 us; speedup vs baseline: 1.0529x; 1.0529x over previous
//
#include <hip/hip_runtime.h>
#include <hip/hip_bf16.h>
#include <stdint.h>

// Problem constants
#define B_    2
#define T_    2048
#define E_    1024
#define H_    16
#define D_    64
#define NTOK  (B_*T_)   // 4096

typedef unsigned short u16;
typedef short s16x8 __attribute__((ext_vector_type(8)));
typedef float f32x4 __attribute__((ext_vector_type(4)));

// ---------- helpers ----------
__device__ __forceinline__ u16 f2bf(float f) {
  uint32_t u = __float_as_uint(f);
  u += 0x7FFFu + ((u >> 16) & 1u);          // RNE
  return (u16)(u >> 16);
}
__device__ __forceinline__ float bf2f(u16 h) {
  return __uint_as_float(((uint32_t)h) << 16);
}
__device__ __forceinline__ void split2(float v, u16 &h, u16 &l) {
  h = f2bf(v);
  l = f2bf(v - bf2f(h));
}

// async global->LDS, 16B per lane (linear dest = wave base + lane*16)
__device__ __forceinline__ void gload_lds16(const void* g, void* l) {
  void* gnc = const_cast<void*>(g);
  __builtin_amdgcn_global_load_lds(
      (__attribute__((address_space(1))) uint32_t*)gnc,
      (__attribute__((address_space(3))) uint32_t*)l, 16, 0, 0);
}

// MFMA via inline asm (D,A,B,C); "+v" ties C=D so compiler tracks the dep.
#define MFMA_BF16(accv, av, bv) \
  asm("v_mfma_f32_16x16x32_bf16 %0, %1, %2, %0" : "+v"(accv) : "v"(av), "v"(bv))

// ---------- split f32 -> bf16 hi/lo ----------
__global__ __launch_bounds__(256) void k_split(const float* __restrict__ in,
                                               u16* __restrict__ hi,
                                               u16* __restrict__ lo, int n4) {
  int i = blockIdx.x * 256 + threadIdx.x;
  if (i >= n4) return;
  float4 v = ((const float4*)in)[i];
  u16 h0,h1,h2,h3,l0,l1,l2,l3;
  split2(v.x,h0,l0); split2(v.y,h1,l1); split2(v.z,h2,l2); split2(v.w,h3,l3);
  ushort4 hv; hv.x=h0; hv.y=h1; hv.z=h2; hv.w=h3;
  ushort4 lv; lv.x=l0; lv.y=l1; lv.z=l2; lv.w=l3;
  ((ushort4*)hi)[i] = hv;
  ((ushort4*)lo)[i] = lv;
}

// ---------- split-bf16 NT GEMM: C[M,N] = A[M,K] * Bt[N,K]^T ----------
// 128xBN tile, BK=32, 256 thr (2x2 waves), 16x16x32 MFMA,
// 3 MFMA/frag (hi*hi + hi*lo + lo*hi). Grid (N/BN, M/128, batches).
// Split-C epilogue: cols >= Nsplit go to C1 (col - Nsplit), else C0.
template<int BN>
__global__ __launch_bounds__(256) void gemm_nt_split(
    const u16* __restrict__ Ahi, const u16* __restrict__ Alo,
    const u16* __restrict__ Bhi, const u16* __restrict__ Blo,
    float* __restrict__ C0, float* __restrict__ C1, int Nsplit, int ldC,
    int M, int N, int K,
    long long sA, long long sB, long long sC, int causal) {
  constexpr int NJ = BN / 32;           // frags per wave in n (4 or 2)
  const int bz = blockIdx.z;
  Ahi += (size_t)bz * sA; Alo += (size_t)bz * sA;
  Bhi += (size_t)bz * sB; Blo += (size_t)bz * sB;
  C0  += (size_t)bz * sC; C1  += (size_t)bz * sC;

  const int m0 = blockIdx.y * 128;
  const int n0 = blockIdx.x * BN;
  const int tid  = threadIdx.x;
  const int lane = tid & 63;
  const int w    = tid >> 6;
  const int wm = w >> 1, wn = w & 1;
  const int kmax = causal ? ((m0 + 128 < K) ? (m0 + 128) : K) : K;

  __shared__ u16 sAhi[128*32], sAlo[128*32], sBhi[BN*32], sBlo[BN*32];

  const int r0 = tid >> 2;            // 0..63
  const int c0 = (tid & 3) * 8;       // k element offset (16B chunks)
  const size_t arow  = (size_t)(m0 + r0) * K;
  const size_t arow2 = (size_t)(m0 + 64 + r0) * K;
  const size_t brow  = (size_t)(n0 + r0) * K;
  const size_t brow2 = (size_t)(n0 + 64 + r0) * K;   // used only if BN==128
  const int ldso = r0 * 32 + c0;      // == tid*16 bytes (linear per wave)

  f32x4 acc[4][NJ] = {};

  for (int k0 = 0; k0 < kmax; k0 += 32) {
    const int kc = k0 + c0;
    gload_lds16(Ahi + arow  + kc, &sAhi[ldso]);
    gload_lds16(Ahi + arow2 + kc, &sAhi[64*32 + ldso]);
    gload_lds16(Alo + arow  + kc, &sAlo[ldso]);
    gload_lds16(Alo + arow2 + kc, &sAlo[64*32 + ldso]);
    gload_lds16(Bhi + brow  + kc, &sBhi[ldso]);
    gload_lds16(Blo + brow  + kc, &sBlo[ldso]);
    if constexpr (BN == 128) {
      gload_lds16(Bhi + brow2 + kc, &sBhi[64*32 + ldso]);
      gload_lds16(Blo + brow2 + kc, &sBlo[64*32 + ldso]);
    }
    __syncthreads();   // compiler drains vmcnt before s_barrier

    const int la = lane & 15;
    const int ka = (lane >> 4) * 8;
    s16x8 ah[4], al[4], bh[NJ], bl[NJ];
    #pragma unroll
    for (int i = 0; i < 4; ++i) {
      const int ar = (wm*64 + i*16 + la) * 32 + ka;
      ah[i] = *(const s16x8*)&sAhi[ar];
      al[i] = *(const s16x8*)&sAlo[ar];
    }
    #pragma unroll
    for (int j = 0; j < NJ; ++j) {
      const int br = (wn*(BN/2) + j*16 + la) * 32 + ka;
      bh[j] = *(const s16x8*)&sBhi[br];
      bl[j] = *(const s16x8*)&sBlo[br];
    }
    #pragma unroll
    for (int i = 0; i < 4; ++i) {
      #pragma unroll
      for (int j = 0; j < NJ; ++j) {
        MFMA_BF16(acc[i][j], al[i], bh[j]);
        MFMA_BF16(acc[i][j], ah[i], bl[j]);
        MFMA_BF16(acc[i][j], ah[i], bh[j]);
      }
    }
    __syncthreads();
  }

  asm volatile("s_nop 7\n\ts_nop 7\n\ts_nop 7" ::);  // MFMA->VALU hazard guard

  const int cr = (lane >> 4) * 4;
  const int cc = lane & 15;
  float* Cb = (n0 >= Nsplit) ? C1 : C0;
  const int nbase = (n0 >= Nsplit) ? n0 - Nsplit : n0;
  #pragma unroll
  for (int i = 0; i < 4; ++i) {
    #pragma unroll
    for (int j = 0; j < NJ; ++j) {
      const size_t row = (size_t)(m0 + wm*64 + i*16 + cr);
      const int col = nbase + wn*(BN/2) + j*16 + cc;
      float* cp = Cb + row * ldC + col;
      cp[0]               = acc[i][j][0];
      cp[(size_t)ldC]     = acc[i][j][1];
      cp[(size_t)2*ldC]   = acc[i][j][2];
      cp[(size_t)3*ldC]   = acc[i][j][3];
    }
  }
}

// ---------- sc2 = ||echo_row||^2 / 32  (one wave per token) ----------
__global__ __launch_bounds__(256) void k_sc2(const float* __restrict__ echo,
                                             float* __restrict__ sc2) {
  int tok  = blockIdx.x * 4 + (threadIdx.x >> 6);
  int lane = threadIdx.x & 63;
  const float4* p = (const float4*)(echo + (size_t)tok * E_);
  float s = 0.f;
  #pragma unroll
  for (int j = 0; j < 4; ++j) {
    float4 v = p[lane + j*64];
    s += v.x*v.x + v.y*v.y + v.z*v.z + v.w*v.w;
  }
  #pragma unroll
  for (int off = 32; off; off >>= 1) s += __shfl_xor(s, off);
  if (lane == 0) sc2[tok] = s * (1.0f/32.0f);
}

// ---------- echo f32 [b][t][e] -> echoT hi/lo bf16 [b][e][t] ----------
__global__ __launch_bounds__(256) void k_tsplit(const float* __restrict__ echo,
                                                u16* __restrict__ Thi,
                                                u16* __restrict__ Tlo) {
  __shared__ float tile[32][33];
  int b = blockIdx.z;
  int t0 = blockIdx.x * 32, e0 = blockIdx.y * 32;
  int lx = threadIdx.x & 31, ly = threadIdx.x >> 5;
  #pragma unroll
  for (int i = 0; i < 32; i += 8)
    tile[ly + i][lx] = echo[((size_t)b*T_ + t0 + ly + i) * E_ + e0 + lx];
  __syncthreads();
  #pragma unroll
  for (int i = 0; i < 32; i += 8) {
    float v = tile[lx][ly + i];
    size_t o = ((size_t)b*E_ + e0 + ly + i) * T_ + t0 + lx;
    u16 h, l; split2(v, h, l);
    Thi[o] = h; Tlo[o] = l;
  }
}

// ---------- ra[b,h,t] = sum_e x[b,t,e]*wr[h,e,t] ----------
// grid (T/256, H, 16 e-chunks of 64) = 2048 blocks -> 8 blocks/CU.
__global__ __launch_bounds__(256) void k_ra(const float* __restrict__ x,
                                            const float* __restrict__ wr,
                                            float* __restrict__ ra) {
  int t  = blockIdx.x * 256 + threadIdx.x;
  int h  = blockIdx.y;
  int ec = blockIdx.z;                       // e-chunk of 64
  const float* wrp = wr + ((size_t)h * E_ + ec * 64) * T_ + t;
  const float* x0  = x + (size_t)t * E_ + ec * 64;
  const float* x1  = x0 + (size_t)T_ * E_;
  float a0 = 0.f, a1 = 0.f;
  #pragma unroll 16
  for (int e = 0; e < 64; ++e) {
    float w = wrp[(size_t)e * T_];
    a0 = fmaf(x0[e], w, a0);
    a1 = fmaf(x1[e], w, a1);
  }
  atomicAdd(&ra[(size_t)h * T_ + t], a0);
  atomicAdd(&ra[(size_t)(H_ + h) * T_ + t], a1);
}

// ---------- RRP pass 1: global max + 64-t chunk sums ----------
__global__ __launch_bounds__(256) void k_rrp1(const float* __restrict__ ra,
    const float* __restrict__ rv, float* __restrict__ gmaxb,
    float* __restrict__ csnum, float* __restrict__ csden) {
  int bh = blockIdx.x;                  // b*16+h
  int b = bh >> 4, h = bh & 15;
  int tid = threadIdx.x;
  const float* rar = ra + (size_t)bh * T_;
  __shared__ float red[256];
  float mx = -1e30f;
  for (int t = tid; t < T_; t += 256) mx = fmaxf(mx, rar[t]);
  red[tid] = mx; __syncthreads();
  for (int s = 128; s > 0; s >>= 1) {
    if (tid < s) red[tid] = fmaxf(red[tid], red[tid + s]);
    __syncthreads();
  }
  float gm = red[0] * 0.125f;
  if (tid == 0) gmaxb[bh] = gm;
  int w = tid >> 6, lane = tid & 63;
  for (int c = w; c < 32; c += 4) {
    float num = 0.f, den = 0.f;
    int t0 = c * 64;
    const float* rvp = rv + ((size_t)b * T_ + t0) * E_ + h * 64 + lane;
    #pragma unroll 4
    for (int i = 0; i < 64; ++i) {
      float wt = __expf(fmaf(rar[t0 + i], 0.125f, -gm));
      num = fmaf(wt, rvp[(size_t)i * E_], num);
      den += wt;
    }
    csnum[((size_t)bh * 32 + c) * 64 + lane] = num;
    if (lane == 0) csden[bh * 32 + c] = den;
  }
}

// ---------- RRP pass 2: carry-in + in-chunk scan, write rrp ----------
__global__ __launch_bounds__(64) void k_rrp2(const float* __restrict__ ra,
    const float* __restrict__ rv, const float* __restrict__ gmaxb,
    const float* __restrict__ csnum, const float* __restrict__ csden,
    float* __restrict__ rrp) {
  int bh = blockIdx.x, c = blockIdx.y;
  int b = bh >> 4, h = bh & 15;
  int lane = threadIdx.x;
  float gm = gmaxb[bh];
  const float* rar = ra + (size_t)bh * T_;
  float num = 0.f, den = 0.f;
  for (int cc = 0; cc < c; ++cc) {
    num += csnum[((size_t)bh * 32 + cc) * 64 + lane];
    den += csden[bh * 32 + cc];
  }
  int t0 = c * 64;
  const float* rvp = rv  + ((size_t)b * T_ + t0) * E_ + h * 64 + lane;
  float*       op  = rrp + ((size_t)b * T_ + t0) * E_ + h * 64 + lane;
  for (int i = 0; i < 64; ++i) {
    float wt = __expf(fmaf(rar[t0 + i], 0.125f, -gm));
    num = fmaf(wt, rvp[(size_t)i * E_], num);
    den += wt;
    op[(size_t)i * E_] = num / den;
  }
}

// ---------- Janus: inclusive prefix-max scan of sc2 (per batch) ----------
__global__ __launch_bounds__(256) void k_pmax(const float* __restrict__ sc2,
                                              float* __restrict__ pmax) {
  int b = blockIdx.x;
  __shared__ float u[T_];
  int tid = threadIdx.x;
  for (int i = tid; i < T_; i += 256) u[i] = sc2[b*T_ + i];
  __syncthreads();
  for (int off = 1; off < T_; off <<= 1) {
    float v[8];
    #pragma unroll
    for (int k = 0; k < 8; ++k) {
      int i = tid + k*256;
      v[k] = (i >= off) ? fmaxf(u[i], u[i-off]) : u[i];
    }
    __syncthreads();
    #pragma unroll
    for (int k = 0; k < 8; ++k) u[tid + k*256] = v[k];
    __syncthreads();
  }
  for (int i = tid; i < T_; i += 256) pmax[b*T_ + i] = u[i];
}

// ---------- Janus: row max m_s = a_s*pmax_s and denominator (wave/row) ----------
__global__ __launch_bounds__(256) void k_jden(const float* __restrict__ sc2,
    const float* __restrict__ pmax, float* __restrict__ jm,
    float* __restrict__ jden) {
  int b = blockIdx.y;
  int s = blockIdx.x * 4 + (threadIdx.x >> 6);
  int lane = threadIdx.x & 63;
  const float* u = sc2 + b*T_;
  float a = u[s];
  float m = a * pmax[b*T_ + s];
  float d = 0.f;
  for (int t = lane; t <= s; t += 64) d += __expf(fmaf(a, u[t], -m));
  #pragma unroll
  for (int off = 32; off; off >>= 1) d += __shfl_xor(d, off);
  if (lane == 0) { jm[b*T_+s] = m; jden[b*T_+s] = d; }
}

// ---------- materialize P (hi/lo bf16), normalized, causal-zeroed ----------
__global__ __launch_bounds__(256) void k_pgen(const float* __restrict__ sc2,
    const float* __restrict__ jm, const float* __restrict__ jden,
    u16* __restrict__ Phi, u16* __restrict__ Plo) {
  int b = blockIdx.z;
  size_t base = ((size_t)blockIdx.x * 256 + threadIdx.x) * 8;
  int s  = (int)(base >> 11);
  int t0 = (int)(base & 2047);
  const float* u = sc2 + b*T_;
  float a = u[s];
  float m = jm[b*T_+s];
  float invd = 1.0f / jden[b*T_+s];
  u16 hh[8], ll[8];
  #pragma unroll
  for (int k = 0; k < 8; ++k) {
    int tt = t0 + k;
    float p = (tt <= s) ? __expf(fmaf(a, u[tt], -m)) * invd : 0.0f;
    split2(p, hh[k], ll[k]);
  }
  size_t o = ((size_t)b*T_ + s) * T_ + t0;
  ushort4 h0; h0.x=hh[0]; h0.y=hh[1]; h0.z=hh[2]; h0.w=hh[3];
  ushort4 h1; h1.x=hh[4]; h1.y=hh[5]; h1.z=hh[6]; h1.w=hh[7];
  ushort4 l0; l0.x=ll[0]; l0.y=ll[1]; l0.z=ll[2]; l0.w=ll[3];
  ushort4 l1; l1.x=ll[4]; l1.y=ll[5]; l1.z=ll[6]; l1.w=ll[7];
  *(ushort4*)(Phi + o)     = h0; *(ushort4*)(Phi + o + 4) = h1;
  *(ushort4*)(Plo + o)     = l0; *(ushort4*)(Plo + o + 4) = l1;
}

// ---------- gated fuse -> bf16 hi/lo ----------
__global__ __launch_bounds__(256) void k_fuse(const float* __restrict__ rrp,
    const float* __restrict__ jan, const float* __restrict__ gate,
    u16* __restrict__ Fhi, u16* __restrict__ Flo) {
  int i = blockIdx.x * 256 + threadIdx.x;      // float4 index
  int h = (i & 255) >> 4;                      // ((i*4) % 1024) / 64
  float g0 = gate[h*2], g1 = gate[h*2+1];
  float mg = fmaxf(g0, g1);
  float e0 = __expf(g0 - mg), e1 = __expf(g1 - mg);
  float inv = 1.0f / (e0 + e1);
  float w0 = e0 * inv, w1 = e1 * inv;
  float4 r = ((const float4*)rrp)[i];
  float4 j = ((const float4*)jan)[i];
  u16 hh[4], ll[4];
  split2(w0*r.x + w1*j.x, hh[0], ll[0]);
  split2(w0*r.y + w1*j.y, hh[1], ll[1]);
  split2(w0*r.z + w1*j.z, hh[2], ll[2]);
  split2(w0*r.w + w1*j.w, hh[3], ll[3]);
  ushort4 hv; hv.x=hh[0]; hv.y=hh[1]; hv.z=hh[2]; hv.w=hh[3];
  ushort4 lv; lv.x=ll[0]; lv.y=ll[1]; lv.z=ll[2]; lv.w=ll[3];
  ((ushort4*)Fhi)[i] = hv;
  ((ushort4*)Flo)[i] = lv;
}

// ---------- launcher ----------
extern "C" void kernel_launch(void* const* d_in, const int* in_sizes, int n_in,
                              void* d_out, int out_size, void* d_ws, size_t ws_size,
                              hipStream_t stream) {
  const float* x    = (const float*)d_in[0];
  const float* wr   = (const float*)d_in[1];
  const float* wvr  = (const float*)d_in[2];
  const float* wj   = (const float*)d_in[3];
  const float* gate = (const float*)d_in[4];
  const float* wo   = (const float*)d_in[5];
  float* out = (float*)d_out;

  char* p = (char*)d_ws;
  auto alloc = [&](size_t bytes) {
    char* r = p;
    p += (bytes + 255) & ~(size_t)255;
    return r;
  };
  // ~124 MB total workspace
  u16* x_hi   = (u16*)alloc((size_t)NTOK*E_*2);
  u16* x_lo   = (u16*)alloc((size_t)NTOK*E_*2);
  // NOTE: wvr_hi and wj_hi MUST be contiguous (fused B, N=2048); same for _lo.
  u16* wvr_hi = (u16*)alloc((size_t)E_*E_*2);
  u16* wj_hi  = (u16*)alloc((size_t)E_*E_*2);
  u16* wvr_lo = (u16*)alloc((size_t)E_*E_*2);
  u16* wj_lo  = (u16*)alloc((size_t)E_*E_*2);
  u16* wo_hi  = (u16*)alloc((size_t)E_*E_*2);
  u16* wo_lo  = (u16*)alloc((size_t)E_*E_*2);
  float* rv   = (float*)alloc((size_t)NTOK*E_*4);   // later reused as jan
  float* echo = (float*)alloc((size_t)NTOK*E_*4);   // later reused as p_hi
  u16* p_lo   = (u16*)alloc((size_t)B_*T_*T_*2);
  u16* eT_hi  = (u16*)alloc((size_t)B_*E_*T_*2);
  u16* eT_lo  = (u16*)alloc((size_t)B_*E_*T_*2);
  float* sc2  = (float*)alloc((size_t)NTOK*4);
  float* ra   = (float*)alloc((size_t)B_*H_*T_*4);
  float* gmaxb= (float*)alloc(32*4);
  float* csnum= (float*)alloc((size_t)32*32*64*4);
  float* csden= (float*)alloc((size_t)32*32*4);
  float* pmaxv= (float*)alloc((size_t)NTOK*4);
  float* jm   = (float*)alloc((size_t)NTOK*4);
  float* jden = (float*)alloc((size_t)NTOK*4);
  float* rrp  = (float*)alloc((size_t)NTOK*E_*4);
  u16* f_hi   = (u16*)alloc((size_t)NTOK*E_*2);
  u16* f_lo   = (u16*)alloc((size_t)NTOK*E_*2);
  u16* p_hi = (u16*)echo;   // alias: echo f32 dead before pgen
  float* jan = rv;          // alias: rv dead before jan GEMM

  int n4;
  // split conversions
  n4 = NTOK*E_/4; k_split<<<dim3((n4+255)/256),256,0,stream>>>(x,   x_hi,   x_lo,   n4);
  n4 = E_*E_/4;   k_split<<<dim3((n4+255)/256),256,0,stream>>>(wvr, wvr_hi, wvr_lo, n4);
                  k_split<<<dim3((n4+255)/256),256,0,stream>>>(wj,  wj_hi,  wj_lo,  n4);
                  k_split<<<dim3((n4+255)/256),256,0,stream>>>(wo,  wo_hi,  wo_lo,  n4);

  // fused: [rv | echo] = x @ [wvr | wj]^T   N=2048, BN=128 -> 512 blocks
  gemm_nt_split<128><<<dim3(16,32,1),256,0,stream>>>(
      x_hi, x_lo, wvr_hi, wvr_lo, rv, echo, /*Nsplit=*/E_, /*ldC=*/E_,
      NTOK, 2*E_, E_, 0,0,0, 0);

  // sc2 (analytic ||echo||^2/sqrt(E)), echoT hi/lo
  k_sc2<<<dim3(NTOK/4),256,0,stream>>>(echo, sc2);
  k_tsplit<<<dim3(T_/32, E_/32, B_),256,0,stream>>>(echo, eT_hi, eT_lo);

  // ra (per-head key scores)
  hipMemsetAsync(ra, 0, (size_t)B_*H_*T_*4, stream);
  k_ra<<<dim3(T_/256, H_, 16),256,0,stream>>>(x, wr, ra);

  // RRP prefix-softmax scan
  k_rrp1<<<dim3(32),256,0,stream>>>(ra, rv, gmaxb, csnum, csden);
  k_rrp2<<<dim3(32,32),64,0,stream>>>(ra, rv, gmaxb, csnum, csden, rrp);

  // Janus stats + P + PV GEMM (causal)
  k_pmax<<<dim3(B_),256,0,stream>>>(sc2, pmaxv);
  k_jden<<<dim3(T_/4, B_),256,0,stream>>>(sc2, pmaxv, jm, jden);
  k_pgen<<<dim3(T_*T_/2048, 1, B_),256,0,stream>>>(sc2, jm, jden, p_hi, p_lo);
  gemm_nt_split<64><<<dim3(16,16,2),256,0,stream>>>(
      p_hi, p_lo, eT_hi, eT_lo, jan, jan, /*Nsplit=*/1<<30, /*ldC=*/E_,
      T_, E_, T_, (long long)T_*T_, (long long)E_*T_, (long long)T_*E_, 1);

  // fuse + final projection
  n4 = NTOK*E_/4;
  k_fuse<<<dim3(n4/256),256,0,stream>>>(rrp, jan, gate, f_hi, f_lo);
  gemm_nt_split<64><<<dim3(16,32,1),256,0,stream>>>(
      f_hi, f_lo, wo_hi, wo_lo, out, out, /*Nsplit=*/1<<30, /*ldC=*/E_,
      NTOK, E_, E_, 0,0,0, 0);
}

// Round 6
// 458.469 us; speedup vs baseline: 1.2308x; 1.1690x over previous
//
#include <hip/hip_runtime.h>
#include <hip/hip_bf16.h>
#include <stdint.h>

// Problem constants
#define B_    2
#define T_    2048
#define E_    1024
#define H_    16
#define D_    64
#define NTOK  (B_*T_)   // 4096

typedef unsigned short u16;
typedef short s16x8 __attribute__((ext_vector_type(8)));
typedef float f32x4 __attribute__((ext_vector_type(4)));

// ---------- helpers ----------
__device__ __forceinline__ u16 f2bf(float f) {
  uint32_t u = __float_as_uint(f);
  u += 0x7FFFu + ((u >> 16) & 1u);          // RNE
  return (u16)(u >> 16);
}
__device__ __forceinline__ float bf2f(u16 h) {
  return __uint_as_float(((uint32_t)h) << 16);
}
__device__ __forceinline__ void split2(float v, u16 &h, u16 &l) {
  h = f2bf(v);
  l = f2bf(v - bf2f(h));
}

// async global->LDS, 16B per lane (HW dest = wave-uniform base + lane*16; our
// per-lane pointer is exactly linear in tid so this matches).
__device__ __forceinline__ void gload_lds16(const void* g, void* l) {
  void* gnc = const_cast<void*>(g);
  __builtin_amdgcn_global_load_lds(
      (__attribute__((address_space(1))) uint32_t*)gnc,
      (__attribute__((address_space(3))) uint32_t*)l, 16, 0, 0);
}

// MFMA via inline asm (D,A,B,C); "+v" ties C=D so compiler tracks the dep.
#define MFMA_BF16(accv, av, bv) \
  asm("v_mfma_f32_16x16x32_bf16 %0, %1, %2, %0" : "+v"(accv) : "v"(av), "v"(bv))

// ---------- split f32 -> bf16 hi/lo ----------
__global__ __launch_bounds__(256) void k_split(const float* __restrict__ in,
                                               u16* __restrict__ hi,
                                               u16* __restrict__ lo, int n4) {
  int i = blockIdx.x * 256 + threadIdx.x;
  if (i >= n4) return;
  float4 v = ((const float4*)in)[i];
  u16 h0,h1,h2,h3,l0,l1,l2,l3;
  split2(v.x,h0,l0); split2(v.y,h1,l1); split2(v.z,h2,l2); split2(v.w,h3,l3);
  ushort4 hv; hv.x=h0; hv.y=h1; hv.z=h2; hv.w=h3;
  ushort4 lv; lv.x=l0; lv.y=l1; lv.z=l2; lv.w=l3;
  ((ushort4*)hi)[i] = hv;
  ((ushort4*)lo)[i] = lv;
}

// ---------- split-bf16 NT GEMM: C[M,N] = A[M,K] * Bt[N,K]^T ----------
// 128xBN tile, BK=32, 256 thr (2x2 waves), 16x16x32 MFMA,
// 3 MFMA/frag (hi*hi + hi*lo + lo*hi). Grid (N/BN, M/128, batches).
// LDS XOR-swizzle (T2, rule #21): physical 16B slot p of row r holds global
// slot p ^ ((r>>1)&3). LDS dest stays linear (gload_lds constraint); the
// permutation is applied on the per-lane GLOBAL source and on ds_read addrs.
// Breaks the 8-way bank conflict of row-major [row][64B] fragment reads.
template<int BN>
__global__ __launch_bounds__(256) void gemm_nt_split(
    const u16* __restrict__ Ahi, const u16* __restrict__ Alo,
    const u16* __restrict__ Bhi, const u16* __restrict__ Blo,
    float* __restrict__ C0, float* __restrict__ C1, int Nsplit, int ldC,
    int M, int N, int K,
    long long sA, long long sB, long long sC, int causal) {
  constexpr int NJ = BN / 32;           // frags per wave in n (4 or 2)
  const int bz = blockIdx.z;
  Ahi += (size_t)bz * sA; Alo += (size_t)bz * sA;
  Bhi += (size_t)bz * sB; Blo += (size_t)bz * sB;
  C0  += (size_t)bz * sC; C1  += (size_t)bz * sC;

  const int m0 = blockIdx.y * 128;
  const int n0 = blockIdx.x * BN;
  const int tid  = threadIdx.x;
  const int lane = tid & 63;
  const int w    = tid >> 6;
  const int wm = w >> 1, wn = w & 1;
  const int kmax = causal ? ((m0 + 128 < K) ? (m0 + 128) : K) : K;

  __shared__ u16 sAhi[128*32], sAlo[128*32], sBhi[BN*32], sBlo[BN*32];

  const int r0 = tid >> 2;            // 0..63 (row within 64-row half)
  // global source column slot, pre-swizzled: (tid&3) ^ ((r0>>1)&3)
  const int c0 = (((tid & 3) ^ ((tid >> 3) & 3)) * 8);
  const int ldso = r0 * 32 + (tid & 3) * 8;   // == tid*16 bytes, LINEAR
  const size_t arow  = (size_t)(m0 + r0) * K;
  const size_t arow2 = (size_t)(m0 + 64 + r0) * K;
  const size_t brow  = (size_t)(n0 + r0) * K;
  const size_t brow2 = (size_t)(n0 + 64 + r0) * K;   // used only if BN==128

  f32x4 acc[4][NJ] = {};

  for (int k0 = 0; k0 < kmax; k0 += 32) {
    const int kc = k0 + c0;
    gload_lds16(Ahi + arow  + kc, &sAhi[ldso]);
    gload_lds16(Ahi + arow2 + kc, &sAhi[64*32 + ldso]);
    gload_lds16(Alo + arow  + kc, &sAlo[ldso]);
    gload_lds16(Alo + arow2 + kc, &sAlo[64*32 + ldso]);
    gload_lds16(Bhi + brow  + kc, &sBhi[ldso]);
    gload_lds16(Blo + brow  + kc, &sBlo[ldso]);
    if constexpr (BN == 128) {
      gload_lds16(Bhi + brow2 + kc, &sBhi[64*32 + ldso]);
      gload_lds16(Blo + brow2 + kc, &sBlo[64*32 + ldso]);
    }
    __syncthreads();   // compiler drains vmcnt before s_barrier

    const int la = lane & 15;
    // swizzled read slot: logical slot (lane>>4) ^ row-key ((lane>>1)&3)
    const int kap = (((lane >> 4) ^ ((lane >> 1) & 3)) * 8);
    s16x8 ah[4], al[4], bh[NJ], bl[NJ];
    #pragma unroll
    for (int i = 0; i < 4; ++i) {
      const int ar = (wm*64 + i*16 + la) * 32 + kap;
      ah[i] = *(const s16x8*)&sAhi[ar];
      al[i] = *(const s16x8*)&sAlo[ar];
    }
    #pragma unroll
    for (int j = 0; j < NJ; ++j) {
      const int br = (wn*(BN/2) + j*16 + la) * 32 + kap;
      bh[j] = *(const s16x8*)&sBhi[br];
      bl[j] = *(const s16x8*)&sBlo[br];
    }
    #pragma unroll
    for (int i = 0; i < 4; ++i) {
      #pragma unroll
      for (int j = 0; j < NJ; ++j) {
        MFMA_BF16(acc[i][j], al[i], bh[j]);
        MFMA_BF16(acc[i][j], ah[i], bl[j]);
        MFMA_BF16(acc[i][j], ah[i], bh[j]);
      }
    }
    __syncthreads();
  }

  asm volatile("s_nop 7\n\ts_nop 7\n\ts_nop 7" ::);  // MFMA->VALU hazard guard

  const int cr = (lane >> 4) * 4;
  const int cc = lane & 15;
  float* Cb = (n0 >= Nsplit) ? C1 : C0;
  const int nbase = (n0 >= Nsplit) ? n0 - Nsplit : n0;
  #pragma unroll
  for (int i = 0; i < 4; ++i) {
    #pragma unroll
    for (int j = 0; j < NJ; ++j) {
      const size_t row = (size_t)(m0 + wm*64 + i*16 + cr);
      const int col = nbase + wn*(BN/2) + j*16 + cc;
      float* cp = Cb + row * ldC + col;
      cp[0]               = acc[i][j][0];
      cp[(size_t)ldC]     = acc[i][j][1];
      cp[(size_t)2*ldC]   = acc[i][j][2];
      cp[(size_t)3*ldC]   = acc[i][j][3];
    }
  }
}

// ---------- sc2 = ||echo_row||^2 / 32  (one wave per token) ----------
__global__ __launch_bounds__(256) void k_sc2(const float* __restrict__ echo,
                                             float* __restrict__ sc2) {
  int tok  = blockIdx.x * 4 + (threadIdx.x >> 6);
  int lane = threadIdx.x & 63;
  const float4* p = (const float4*)(echo + (size_t)tok * E_);
  float s = 0.f;
  #pragma unroll
  for (int j = 0; j < 4; ++j) {
    float4 v = p[lane + j*64];
    s += v.x*v.x + v.y*v.y + v.z*v.z + v.w*v.w;
  }
  #pragma unroll
  for (int off = 32; off; off >>= 1) s += __shfl_xor(s, off);
  if (lane == 0) sc2[tok] = s * (1.0f/32.0f);
}

// ---------- echo f32 [b][t][e] -> echoT hi/lo bf16 [b][e][t] ----------
__global__ __launch_bounds__(256) void k_tsplit(const float* __restrict__ echo,
                                                u16* __restrict__ Thi,
                                                u16* __restrict__ Tlo) {
  __shared__ float tile[32][33];
  int b = blockIdx.z;
  int t0 = blockIdx.x * 32, e0 = blockIdx.y * 32;
  int lx = threadIdx.x & 31, ly = threadIdx.x >> 5;
  #pragma unroll
  for (int i = 0; i < 32; i += 8)
    tile[ly + i][lx] = echo[((size_t)b*T_ + t0 + ly + i) * E_ + e0 + lx];
  __syncthreads();
  #pragma unroll
  for (int i = 0; i < 32; i += 8) {
    float v = tile[lx][ly + i];
    size_t o = ((size_t)b*E_ + e0 + ly + i) * T_ + t0 + lx;
    u16 h, l; split2(v, h, l);
    Thi[o] = h; Tlo[o] = l;
  }
}

// ---------- ra[b,h,t] = sum_e x[b,t,e]*wr[h,e,t] ----------
// LDS-tiled: block = (t-tile 64, e-chunk 32, 4 heads), x staged once, wave w
// owns head hg*4+w. grid (32, 32, 4) = 4096 blocks, 8/CU, x re-read 4x not 16x.
__global__ __launch_bounds__(256) void k_ra(const float* __restrict__ x,
                                            const float* __restrict__ wr,
                                            float* __restrict__ ra) {
  __shared__ float xs[2][32][65];
  const int tid  = threadIdx.x;
  const int lane = tid & 63;
  const int t0 = blockIdx.x * 64;
  const int e0 = blockIdx.y * 32;
  const int h  = blockIdx.z * 4 + (tid >> 6);
  #pragma unroll
  for (int b = 0; b < 2; ++b)
    #pragma unroll
    for (int p = 0; p < 2; ++p) {
      const int ee = (tid & 3) * 4 + p * 16;
      const int tt = tid >> 2;
      float4 v = *(const float4*)&x[((size_t)b*T_ + t0 + tt) * E_ + e0 + ee];
      xs[b][ee+0][tt] = v.x; xs[b][ee+1][tt] = v.y;
      xs[b][ee+2][tt] = v.z; xs[b][ee+3][tt] = v.w;
    }
  __syncthreads();
  const float* wrp = wr + ((size_t)h * E_ + e0) * T_ + t0 + lane;
  float a0 = 0.f, a1 = 0.f;
  #pragma unroll 8
  for (int e = 0; e < 32; ++e) {
    float wv = wrp[(size_t)e * T_];
    a0 = fmaf(xs[0][e][lane], wv, a0);
    a1 = fmaf(xs[1][e][lane], wv, a1);
  }
  atomicAdd(&ra[(size_t)h * T_ + t0 + lane], a0);
  atomicAdd(&ra[(size_t)(H_ + h) * T_ + t0 + lane], a1);
}

// ---------- RRP: global max per (b,h) ----------
__global__ __launch_bounds__(256) void k_gmax(const float* __restrict__ ra,
                                              float* __restrict__ gmaxb) {
  int bh = blockIdx.x;
  int tid = threadIdx.x;
  const float* rar = ra + (size_t)bh * T_;
  __shared__ float red[256];
  float mx = -1e30f;
  for (int t = tid; t < T_; t += 256) mx = fmaxf(mx, rar[t]);
  red[tid] = mx; __syncthreads();
  for (int s = 128; s > 0; s >>= 1) {
    if (tid < s) red[tid] = fmaxf(red[tid], red[tid + s]);
    __syncthreads();
  }
  if (tid == 0) gmaxb[bh] = red[0] * 0.125f;
}

// ---------- RRP: 64-t chunk sums (one wave per (bh, chunk)) ----------
__global__ __launch_bounds__(64) void k_csum(const float* __restrict__ ra,
    const float* __restrict__ rv, const float* __restrict__ gmaxb,
    float* __restrict__ csnum, float* __restrict__ csden) {
  int bh = blockIdx.x, c = blockIdx.y;
  int b = bh >> 4, h = bh & 15;
  int lane = threadIdx.x;
  float gm = gmaxb[bh];
  const float* rar = ra + (size_t)bh * T_;
  int t0 = c * 64;
  const float* rvp = rv + ((size_t)b * T_ + t0) * E_ + h * 64 + lane;
  float num = 0.f, den = 0.f;
  #pragma unroll 4
  for (int i = 0; i < 64; ++i) {
    float wt = __expf(fmaf(rar[t0 + i], 0.125f, -gm));
    num = fmaf(wt, rvp[(size_t)i * E_], num);
    den += wt;
  }
  csnum[((size_t)bh * 32 + c) * 64 + lane] = num;
  if (lane == 0) csden[bh * 32 + c] = den;
}

// ---------- RRP pass 2: carry-in + in-chunk scan, write rrp ----------
__global__ __launch_bounds__(64) void k_rrp2(const float* __restrict__ ra,
    const float* __restrict__ rv, const float* __restrict__ gmaxb,
    const float* __restrict__ csnum, const float* __restrict__ csden,
    float* __restrict__ rrp) {
  int bh = blockIdx.x, c = blockIdx.y;
  int b = bh >> 4, h = bh & 15;
  int lane = threadIdx.x;
  float gm = gmaxb[bh];
  const float* rar = ra + (size_t)bh * T_;
  float num = 0.f, den = 0.f;
  for (int cc = 0; cc < c; ++cc) {
    num += csnum[((size_t)bh * 32 + cc) * 64 + lane];
    den += csden[bh * 32 + cc];
  }
  int t0 = c * 64;
  const float* rvp = rv  + ((size_t)b * T_ + t0) * E_ + h * 64 + lane;
  float*       op  = rrp + ((size_t)b * T_ + t0) * E_ + h * 64 + lane;
  for (int i = 0; i < 64; ++i) {
    float wt = __expf(fmaf(rar[t0 + i], 0.125f, -gm));
    num = fmaf(wt, rvp[(size_t)i * E_], num);
    den += wt;
    op[(size_t)i * E_] = num / den;
  }
}

// ---------- Janus: inclusive prefix-max scan of sc2 (per batch) ----------
__global__ __launch_bounds__(256) void k_pmax(const float* __restrict__ sc2,
                                              float* __restrict__ pmax) {
  int b = blockIdx.x;
  __shared__ float u[T_];
  int tid = threadIdx.x;
  for (int i = tid; i < T_; i += 256) u[i] = sc2[b*T_ + i];
  __syncthreads();
  for (int off = 1; off < T_; off <<= 1) {
    float v[8];
    #pragma unroll
    for (int k = 0; k < 8; ++k) {
      int i = tid + k*256;
      v[k] = (i >= off) ? fmaxf(u[i], u[i-off]) : u[i];
    }
    __syncthreads();
    #pragma unroll
    for (int k = 0; k < 8; ++k) u[tid + k*256] = v[k];
    __syncthreads();
  }
  for (int i = tid; i < T_; i += 256) pmax[b*T_ + i] = u[i];
}

// ---------- Janus: row max m_s = a_s*pmax_s and denominator (wave/row) ----------
__global__ __launch_bounds__(256) void k_jden(const float* __restrict__ sc2,
    const float* __restrict__ pmax, float* __restrict__ jm,
    float* __restrict__ jden) {
  int b = blockIdx.y;
  int s = blockIdx.x * 4 + (threadIdx.x >> 6);
  int lane = threadIdx.x & 63;
  const float* u = sc2 + b*T_;
  float a = u[s];
  float m = a * pmax[b*T_ + s];
  float d = 0.f;
  for (int t = lane; t <= s; t += 64) d += __expf(fmaf(a, u[t], -m));
  #pragma unroll
  for (int off = 32; off; off >>= 1) d += __shfl_xor(d, off);
  if (lane == 0) { jm[b*T_+s] = m; jden[b*T_+s] = d; }
}

// ---------- materialize P (hi/lo bf16), normalized, causal-zeroed ----------
__global__ __launch_bounds__(256) void k_pgen(const float* __restrict__ sc2,
    const float* __restrict__ jm, const float* __restrict__ jden,
    u16* __restrict__ Phi, u16* __restrict__ Plo) {
  int b = blockIdx.z;
  size_t base = ((size_t)blockIdx.x * 256 + threadIdx.x) * 8;
  int s  = (int)(base >> 11);
  int t0 = (int)(base & 2047);
  const float* u = sc2 + b*T_;
  float a = u[s];
  float m = jm[b*T_+s];
  float invd = 1.0f / jden[b*T_+s];
  u16 hh[8], ll[8];
  #pragma unroll
  for (int k = 0; k < 8; ++k) {
    int tt = t0 + k;
    float p = (tt <= s) ? __expf(fmaf(a, u[tt], -m)) * invd : 0.0f;
    split2(p, hh[k], ll[k]);
  }
  size_t o = ((size_t)b*T_ + s) * T_ + t0;
  ushort4 h0; h0.x=hh[0]; h0.y=hh[1]; h0.z=hh[2]; h0.w=hh[3];
  ushort4 h1; h1.x=hh[4]; h1.y=hh[5]; h1.z=hh[6]; h1.w=hh[7];
  ushort4 l0; l0.x=ll[0]; l0.y=ll[1]; l0.z=ll[2]; l0.w=ll[3];
  ushort4 l1; l1.x=ll[4]; l1.y=ll[5]; l1.z=ll[6]; l1.w=ll[7];
  *(ushort4*)(Phi + o)     = h0; *(ushort4*)(Phi + o + 4) = h1;
  *(ushort4*)(Plo + o)     = l0; *(ushort4*)(Plo + o + 4) = l1;
}

// ---------- gated fuse -> bf16 hi/lo ----------
__global__ __launch_bounds__(256) void k_fuse(const float* __restrict__ rrp,
    const float* __restrict__ jan, const float* __restrict__ gate,
    u16* __restrict__ Fhi, u16* __restrict__ Flo) {
  int i = blockIdx.x * 256 + threadIdx.x;      // float4 index
  int h = (i & 255) >> 4;                      // ((i*4) % 1024) / 64
  float g0 = gate[h*2], g1 = gate[h*2+1];
  float mg = fmaxf(g0, g1);
  float e0 = __expf(g0 - mg), e1 = __expf(g1 - mg);
  float inv = 1.0f / (e0 + e1);
  float w0 = e0 * inv, w1 = e1 * inv;
  float4 r = ((const float4*)rrp)[i];
  float4 j = ((const float4*)jan)[i];
  u16 hh[4], ll[4];
  split2(w0*r.x + w1*j.x, hh[0], ll[0]);
  split2(w0*r.y + w1*j.y, hh[1], ll[1]);
  split2(w0*r.z + w1*j.z, hh[2], ll[2]);
  split2(w0*r.w + w1*j.w, hh[3], ll[3]);
  ushort4 hv; hv.x=hh[0]; hv.y=hh[1]; hv.z=hh[2]; hv.w=hh[3];
  ushort4 lv; lv.x=ll[0]; lv.y=ll[1]; lv.z=ll[2]; lv.w=ll[3];
  ((ushort4*)Fhi)[i] = hv;
  ((ushort4*)Flo)[i] = lv;
}

// ---------- launcher ----------
extern "C" void kernel_launch(void* const* d_in, const int* in_sizes, int n_in,
                              void* d_out, int out_size, void* d_ws, size_t ws_size,
                              hipStream_t stream) {
  const float* x    = (const float*)d_in[0];
  const float* wr   = (const float*)d_in[1];
  const float* wvr  = (const float*)d_in[2];
  const float* wj   = (const float*)d_in[3];
  const float* gate = (const float*)d_in[4];
  const float* wo   = (const float*)d_in[5];
  float* out = (float*)d_out;

  char* p = (char*)d_ws;
  auto alloc = [&](size_t bytes) {
    char* r = p;
    p += (bytes + 255) & ~(size_t)255;
    return r;
  };
  // ~124 MB total workspace
  u16* x_hi   = (u16*)alloc((size_t)NTOK*E_*2);
  u16* x_lo   = (u16*)alloc((size_t)NTOK*E_*2);
  // NOTE: wvr_hi and wj_hi MUST be contiguous (fused B, N=2048); same for _lo.
  u16* wvr_hi = (u16*)alloc((size_t)E_*E_*2);
  u16* wj_hi  = (u16*)alloc((size_t)E_*E_*2);
  u16* wvr_lo = (u16*)alloc((size_t)E_*E_*2);
  u16* wj_lo  = (u16*)alloc((size_t)E_*E_*2);
  u16* wo_hi  = (u16*)alloc((size_t)E_*E_*2);
  u16* wo_lo  = (u16*)alloc((size_t)E_*E_*2);
  float* rv   = (float*)alloc((size_t)NTOK*E_*4);   // later reused as jan
  float* echo = (float*)alloc((size_t)NTOK*E_*4);   // later reused as p_hi
  u16* p_lo   = (u16*)alloc((size_t)B_*T_*T_*2);
  u16* eT_hi  = (u16*)alloc((size_t)B_*E_*T_*2);
  u16* eT_lo  = (u16*)alloc((size_t)B_*E_*T_*2);
  float* sc2  = (float*)alloc((size_t)NTOK*4);
  float* ra   = (float*)alloc((size_t)B_*H_*T_*4);
  float* gmaxb= (float*)alloc(32*4);
  float* csnum= (float*)alloc((size_t)32*32*64*4);
  float* csden= (float*)alloc((size_t)32*32*4);
  float* pmaxv= (float*)alloc((size_t)NTOK*4);
  float* jm   = (float*)alloc((size_t)NTOK*4);
  float* jden = (float*)alloc((size_t)NTOK*4);
  float* rrp  = (float*)alloc((size_t)NTOK*E_*4);
  u16* f_hi   = (u16*)alloc((size_t)NTOK*E_*2);
  u16* f_lo   = (u16*)alloc((size_t)NTOK*E_*2);
  u16* p_hi = (u16*)echo;   // alias: echo f32 dead before pgen
  float* jan = rv;          // alias: rv dead before jan GEMM

  int n4;
  // split conversions
  n4 = NTOK*E_/4; k_split<<<dim3((n4+255)/256),256,0,stream>>>(x,   x_hi,   x_lo,   n4);
  n4 = E_*E_/4;   k_split<<<dim3((n4+255)/256),256,0,stream>>>(wvr, wvr_hi, wvr_lo, n4);
                  k_split<<<dim3((n4+255)/256),256,0,stream>>>(wj,  wj_hi,  wj_lo,  n4);
                  k_split<<<dim3((n4+255)/256),256,0,stream>>>(wo,  wo_hi,  wo_lo,  n4);

  // fused: [rv | echo] = x @ [wvr | wj]^T   N=2048, BN=128 -> 512 blocks
  gemm_nt_split<128><<<dim3(16,32,1),256,0,stream>>>(
      x_hi, x_lo, wvr_hi, wvr_lo, rv, echo, /*Nsplit=*/E_, /*ldC=*/E_,
      NTOK, 2*E_, E_, 0,0,0, 0);

  // sc2 (analytic ||echo||^2/sqrt(E)), echoT hi/lo
  k_sc2<<<dim3(NTOK/4),256,0,stream>>>(echo, sc2);
  k_tsplit<<<dim3(T_/32, E_/32, B_),256,0,stream>>>(echo, eT_hi, eT_lo);

  // ra (per-head key scores)
  hipMemsetAsync(ra, 0, (size_t)B_*H_*T_*4, stream);
  k_ra<<<dim3(T_/64, E_/32, H_/4),256,0,stream>>>(x, wr, ra);

  // RRP prefix-softmax scan
  k_gmax<<<dim3(32),256,0,stream>>>(ra, gmaxb);
  k_csum<<<dim3(32,32),64,0,stream>>>(ra, rv, gmaxb, csnum, csden);
  k_rrp2<<<dim3(32,32),64,0,stream>>>(ra, rv, gmaxb, csnum, csden, rrp);

  // Janus stats + P + PV GEMM (causal)
  k_pmax<<<dim3(B_),256,0,stream>>>(sc2, pmaxv);
  k_jden<<<dim3(T_/4, B_),256,0,stream>>>(sc2, pmaxv, jm, jden);
  k_pgen<<<dim3(T_*T_/2048, 1, B_),256,0,stream>>>(sc2, jm, jden, p_hi, p_lo);
  gemm_nt_split<64><<<dim3(16,16,2),256,0,stream>>>(
      p_hi, p_lo, eT_hi, eT_lo, jan, jan, /*Nsplit=*/1<<30, /*ldC=*/E_,
      T_, E_, T_, (long long)T_*T_, (long long)E_*T_, (long long)T_*E_, 1);

  // fuse + final projection
  n4 = NTOK*E_/4;
  k_fuse<<<dim3(n4/256),256,0,stream>>>(rrp, jan, gate, f_hi, f_lo);
  gemm_nt_split<64><<<dim3(16,32,1),256,0,stream>>>(
      f_hi, f_lo, wo_hi, wo_lo, out, out, /*Nsplit=*/1<<30, /*ldC=*/E_,
      NTOK, E_, E_, 0,0,0, 0);
}